// Round 2
// baseline (2250.279 us; speedup 1.0000x reference)
//
#include <hip/hip_runtime.h>
#include <hip/hip_bf16.h>

#define GAMMA 0.05f
#define LNEPS 1e-12f
#define HDIMT 768
#define SDIM  2048
#define NHEAD 12
#define HDHEAD 64
#define MTOT  4096
#define BHEADS 24
#define OUT0E ((size_t)MTOT * HDIMT)   // element offset of probs in d_out

__device__ __forceinline__ float bf2f(unsigned short u) {
    union { unsigned int i; float f; } c; c.i = ((unsigned int)u) << 16; return c.f;
}
__device__ __forceinline__ unsigned short f2bf(float f) {
    union { float f; unsigned int i; } c; c.f = f;
    unsigned int i = c.i;
    i += 0x7FFFu + ((i >> 16) & 1u);
    return (unsigned short)(i >> 16);
}

__device__ __forceinline__ void load8f(const void* p, size_t idx, int isbf, float* r) {
    if (isbf) {
        const unsigned short* b = (const unsigned short*)p + idx;
        uint4 u = *(const uint4*)b;
        const unsigned short* pu = (const unsigned short*)&u;
        #pragma unroll
        for (int j = 0; j < 8; ++j) r[j] = bf2f(pu[j]);
    } else {
        const float* f = (const float*)p + idx;
        float4 a = *(const float4*)f, c = *(const float4*)(f + 4);
        r[0] = a.x; r[1] = a.y; r[2] = a.z; r[3] = a.w;
        r[4] = c.x; r[5] = c.y; r[6] = c.z; r[7] = c.w;
    }
}
__device__ __forceinline__ float load1f(const void* p, size_t idx, int isbf) {
    return isbf ? bf2f(((const unsigned short*)p)[idx]) : ((const float*)p)[idx];
}

__global__ void detect_kernel(const void* __restrict__ x, int* __restrict__ flag) {
    __shared__ int cnt;
    if (threadIdx.x == 0) cnt = 0;
    __syncthreads();
    const unsigned short* u = (const unsigned short*)x;
    unsigned short v = u[2 * threadIdx.x];
    int e = (v >> 7) & 0xFF;
    int ok = (e >= 100 && e <= 140) ? 1 : 0;
    atomicAdd(&cnt, ok);
    __syncthreads();
    if (threadIdx.x == 0) flag[0] = (cnt >= 192) ? 1 : 0;
}

__global__ __launch_bounds__(256) void qkv_kernel(
    const void* __restrict__ x,
    const void* __restrict__ Wq, const void* __restrict__ bq,
    const void* __restrict__ Wk, const void* __restrict__ bk,
    const void* __restrict__ Wv, const void* __restrict__ bv,
    float* __restrict__ qo, float* __restrict__ ko, float* __restrict__ vo,
    const int* __restrict__ flag)
{
    __shared__ float a_s[64][36];
    __shared__ float b_s[64][36];

    const int isbf = flag[0];
    const int tid = threadIdx.x;
    const int tx = tid & 15, ty = tid >> 4;
    const int m0 = blockIdx.x * 64;
    const int h  = blockIdx.y;
    const int n0 = h * 64;
    const int z  = blockIdx.z;

    const void* W    = (z == 0) ? Wq : (z == 1) ? Wk : Wv;
    const void* bias = (z == 0) ? bq : (z == 1) ? bk : bv;
    float* out = (z == 0) ? qo : (z == 1) ? ko : vo;

    const int lr = tid >> 2;
    const int lc = (tid & 3) * 8;

    float acc[4][4] = {};

    for (int k0 = 0; k0 < HDIMT; k0 += 32) {
        __syncthreads();
        {
            float av[8], bv8[8];
            load8f(x, (size_t)(m0 + lr) * HDIMT + k0 + lc, isbf, av);
            load8f(W, (size_t)(n0 + lr) * HDIMT + k0 + lc, isbf, bv8);
            #pragma unroll
            for (int j = 0; j < 8; ++j) a_s[lr][lc + j] = av[j];
            #pragma unroll
            for (int j = 0; j < 8; ++j) b_s[lr][lc + j] = bv8[j];
        }
        __syncthreads();
        #pragma unroll
        for (int kk = 0; kk < 32; kk += 4) {
            float4 a4[4], b4[4];
            #pragma unroll
            for (int i = 0; i < 4; ++i) a4[i] = *(const float4*)&a_s[ty * 4 + i][kk];
            #pragma unroll
            for (int j = 0; j < 4; ++j) b4[j] = *(const float4*)&b_s[tx * 4 + j][kk];
            #pragma unroll
            for (int i = 0; i < 4; ++i)
                #pragma unroll
                for (int j = 0; j < 4; ++j)
                    acc[i][j] += a4[i].x * b4[j].x + a4[i].y * b4[j].y +
                                 a4[i].z * b4[j].z + a4[i].w * b4[j].w;
        }
    }

    float bb[4];
    #pragma unroll
    for (int j = 0; j < 4; ++j) bb[j] = load1f(bias, n0 + tx * 4 + j, isbf);

    #pragma unroll
    for (int i = 0; i < 4; ++i) {
        const int m = m0 + ty * 4 + i;
        const int b = m >> 11;
        const int s = m & 2047;
        float4 o;
        o.x = acc[i][0] + bb[0];
        o.y = acc[i][1] + bb[1];
        o.z = acc[i][2] + bb[2];
        o.w = acc[i][3] + bb[3];
        *(float4*)(out + ((size_t)(b * NHEAD + h) * SDIM + s) * HDHEAD + tx * 4) = o;
    }
}

__global__ __launch_bounds__(256) void attn_kernel(
    const float* __restrict__ qws, const float* __restrict__ kws,
    const float* __restrict__ vws,
    float* __restrict__ ctx, void* __restrict__ dout,
    const int* __restrict__ flag)
{
    __shared__ float q_s[64][68];
    __shared__ float k_s[64][68];
    __shared__ float vT[64][68];
    __shared__ float m_row[64], li_row[64];

    const int isbf = flag[0];
    const int tid = threadIdx.x;
    const int tx = tid & 15, ty = tid >> 4;
    const int bh = blockIdx.y;
    const int r0 = blockIdx.x * 64;

    const int lr = tid >> 2;
    const int lc = (tid & 3) * 16;

    {
        const float* qp = qws + ((size_t)bh * SDIM + r0 + lr) * HDHEAD + lc;
        #pragma unroll
        for (int j = 0; j < 16; j += 4)
            *(float4*)&q_s[lr][lc + j] = *(const float4*)(qp + j);
    }

    float m_run[4], l_run[4];
    #pragma unroll
    for (int i = 0; i < 4; ++i) { m_run[i] = -1e30f; l_run[i] = 0.0f; }

    for (int kt = 0; kt < 32; ++kt) {
        const int t0 = kt * 64;
        __syncthreads();
        {
            const float* kp = kws + ((size_t)bh * SDIM + t0 + lr) * HDHEAD + lc;
            #pragma unroll
            for (int j = 0; j < 16; j += 4)
                *(float4*)&k_s[lr][lc + j] = *(const float4*)(kp + j);
        }
        __syncthreads();

        float sc[4][4] = {};
        #pragma unroll
        for (int d0 = 0; d0 < 64; d0 += 4) {
            float4 a4[4], b4[4];
            #pragma unroll
            for (int i = 0; i < 4; ++i) a4[i] = *(const float4*)&q_s[ty * 4 + i][d0];
            #pragma unroll
            for (int j = 0; j < 4; ++j) b4[j] = *(const float4*)&k_s[tx * 4 + j][d0];
            #pragma unroll
            for (int i = 0; i < 4; ++i)
                #pragma unroll
                for (int j = 0; j < 4; ++j)
                    sc[i][j] += a4[i].x * b4[j].x + a4[i].y * b4[j].y +
                                a4[i].z * b4[j].z + a4[i].w * b4[j].w;
        }
        #pragma unroll
        for (int i = 0; i < 4; ++i) {
            float tm = fmaxf(fmaxf(sc[i][0], sc[i][1]), fmaxf(sc[i][2], sc[i][3]));
            float mn = fmaxf(m_run[i], tm);
            float ls = __expf(sc[i][0] - mn) + __expf(sc[i][1] - mn) +
                       __expf(sc[i][2] - mn) + __expf(sc[i][3] - mn);
            l_run[i] = l_run[i] * __expf(m_run[i] - mn) + ls;
            m_run[i] = mn;
        }
    }

    __syncthreads();
    #pragma unroll
    for (int i = 0; i < 4; ++i) {
        k_s[ty * 4 + i][tx] = m_run[i];
        vT[ty * 4 + i][tx]  = l_run[i];
    }
    __syncthreads();
    if (tid < 64) {
        float mf = -1e30f;
        for (int j = 0; j < 16; ++j) mf = fmaxf(mf, k_s[tid][j]);
        float lf = 0.0f;
        for (int j = 0; j < 16; ++j) lf += vT[tid][j] * __expf(k_s[tid][j] - mf);
        m_row[tid]  = mf;
        li_row[tid] = 1.0f / lf;
    }
    __syncthreads();

    float acc[4][4] = {};
    for (int kt = 0; kt < 32; ++kt) {
        const int t0 = kt * 64;
        {
            const float* kp = kws + ((size_t)bh * SDIM + t0 + lr) * HDHEAD + lc;
            #pragma unroll
            for (int j = 0; j < 16; j += 4)
                *(float4*)&k_s[lr][lc + j] = *(const float4*)(kp + j);
            const float* vp = vws + ((size_t)bh * SDIM + t0 + lr) * HDHEAD + lc;
            #pragma unroll
            for (int j = 0; j < 16; j += 4) {
                float4 vv = *(const float4*)(vp + j);
                vT[lc + j + 0][lr] = vv.x;
                vT[lc + j + 1][lr] = vv.y;
                vT[lc + j + 2][lr] = vv.z;
                vT[lc + j + 3][lr] = vv.w;
            }
        }
        __syncthreads();

        float sc[4][4] = {};
        #pragma unroll
        for (int d0 = 0; d0 < 64; d0 += 4) {
            float4 a4[4], b4[4];
            #pragma unroll
            for (int i = 0; i < 4; ++i) a4[i] = *(const float4*)&q_s[ty * 4 + i][d0];
            #pragma unroll
            for (int j = 0; j < 4; ++j) b4[j] = *(const float4*)&k_s[tx * 4 + j][d0];
            #pragma unroll
            for (int i = 0; i < 4; ++i)
                #pragma unroll
                for (int j = 0; j < 4; ++j)
                    sc[i][j] += a4[i].x * b4[j].x + a4[i].y * b4[j].y +
                                a4[i].z * b4[j].z + a4[i].w * b4[j].w;
        }
        __syncthreads();

        #pragma unroll
        for (int i = 0; i < 4; ++i) {
            const int r = ty * 4 + i;
            const float mv = m_row[r], li = li_row[r];
            float p0 = __expf(sc[i][0] - mv) * li;
            float p1 = __expf(sc[i][1] - mv) * li;
            float p2 = __expf(sc[i][2] - mv) * li;
            float p3 = __expf(sc[i][3] - mv) * li;
            const size_t off = OUT0E + ((size_t)bh * SDIM + r0 + r) * SDIM + t0 + tx * 4;
            if (isbf) {
                ushort4 pu;
                pu.x = f2bf(p0); pu.y = f2bf(p1); pu.z = f2bf(p2); pu.w = f2bf(p3);
                *(ushort4*)((unsigned short*)dout + off) = pu;
            } else {
                float4 pw; pw.x = p0; pw.y = p1; pw.z = p2; pw.w = p3;
                *(float4*)((float*)dout + off) = pw;
            }
            float4 pf; pf.x = p0; pf.y = p1; pf.z = p2; pf.w = p3;
            *(float4*)&k_s[r][tx * 4] = pf;
        }
        __syncthreads();

        #pragma unroll
        for (int t = 0; t < 64; t += 4) {
            float4 a4[4], b4[4];
            #pragma unroll
            for (int i = 0; i < 4; ++i) a4[i] = *(const float4*)&k_s[ty * 4 + i][t];
            #pragma unroll
            for (int j = 0; j < 4; ++j) b4[j] = *(const float4*)&vT[tx * 4 + j][t];
            #pragma unroll
            for (int i = 0; i < 4; ++i)
                #pragma unroll
                for (int j = 0; j < 4; ++j)
                    acc[i][j] += a4[i].x * b4[j].x + a4[i].y * b4[j].y +
                                 a4[i].z * b4[j].z + a4[i].w * b4[j].w;
        }
        __syncthreads();
    }

    const int b = bh / NHEAD, h = bh % NHEAD;
    #pragma unroll
    for (int i = 0; i < 4; ++i) {
        const int r = r0 + ty * 4 + i;
        float4 o; o.x = acc[i][0]; o.y = acc[i][1]; o.z = acc[i][2]; o.w = acc[i][3];
        *(float4*)(ctx + ((size_t)(b * SDIM + r)) * HDIMT + h * HDHEAD + tx * 4) = o;
    }
}

__global__ __launch_bounds__(256) void oproj_kernel(
    const float* __restrict__ ctx,
    const void* __restrict__ Wo, const void* __restrict__ bo,
    const void* __restrict__ x, float* __restrict__ y,
    const int* __restrict__ flag)
{
    __shared__ float a_s[64][36];
    __shared__ float b_s[64][36];

    const int isbf = flag[0];
    const int tid = threadIdx.x;
    const int tx = tid & 15, ty = tid >> 4;
    const int m0 = blockIdx.x * 64, n0 = blockIdx.y * 64;
    const int lr = tid >> 2, lc = (tid & 3) * 8;

    float acc[4][4] = {};

    for (int k0 = 0; k0 < HDIMT; k0 += 32) {
        __syncthreads();
        {
            const float* ap = ctx + (size_t)(m0 + lr) * HDIMT + k0 + lc;
            *(float4*)&a_s[lr][lc]     = *(const float4*)ap;
            *(float4*)&a_s[lr][lc + 4] = *(const float4*)(ap + 4);

            float wv[8];
            load8f(Wo, (size_t)(n0 + lr) * HDIMT + k0 + lc, isbf, wv);
            #pragma unroll
            for (int j = 0; j < 8; ++j)
                b_s[lr][lc + j] = wv[j] + GAMMA * fmaxf(wv[j], 0.0f);
        }
        __syncthreads();
        #pragma unroll
        for (int kk = 0; kk < 32; kk += 4) {
            float4 a4[4], b4[4];
            #pragma unroll
            for (int i = 0; i < 4; ++i) a4[i] = *(const float4*)&a_s[ty * 4 + i][kk];
            #pragma unroll
            for (int j = 0; j < 4; ++j) b4[j] = *(const float4*)&b_s[tx * 4 + j][kk];
            #pragma unroll
            for (int i = 0; i < 4; ++i)
                #pragma unroll
                for (int j = 0; j < 4; ++j)
                    acc[i][j] += a4[i].x * b4[j].x + a4[i].y * b4[j].y +
                                 a4[i].z * b4[j].z + a4[i].w * b4[j].w;
        }
    }

    float pb[4];
    #pragma unroll
    for (int j = 0; j < 4; ++j) {
        float bb = load1f(bo, n0 + tx * 4 + j, isbf);
        pb[j] = bb + GAMMA * fmaxf(bb, 0.0f);
    }

    #pragma unroll
    for (int i = 0; i < 4; ++i) {
        const int m = m0 + ty * 4 + i;
        const size_t xb = (size_t)m * HDIMT + n0 + tx * 4;
        float4 o;
        o.x = acc[i][0] + pb[0] + load1f(x, xb + 0, isbf);
        o.y = acc[i][1] + pb[1] + load1f(x, xb + 1, isbf);
        o.z = acc[i][2] + pb[2] + load1f(x, xb + 2, isbf);
        o.w = acc[i][3] + pb[3] + load1f(x, xb + 3, isbf);
        *(float4*)(y + (size_t)m * HDIMT + n0 + tx * 4) = o;
    }
}

__global__ __launch_bounds__(256) void ln_kernel(
    const float* __restrict__ y, void* __restrict__ out,
    const int* __restrict__ flag)
{
    __shared__ float red[256];
    const int isbf = flag[0];
    const int m = blockIdx.x;
    const int tid = threadIdx.x;
    const float* yr = y + (size_t)m * HDIMT;

    float v0 = yr[tid], v1 = yr[tid + 256], v2 = yr[tid + 512];

    red[tid] = v0 + v1 + v2;
    __syncthreads();
    for (int s = 128; s > 0; s >>= 1) {
        if (tid < s) red[tid] += red[tid + s];
        __syncthreads();
    }
    const float mean = red[0] * (1.0f / 768.0f);
    __syncthreads();

    const float d0 = v0 - mean, d1 = v1 - mean, d2 = v2 - mean;
    red[tid] = d0 * d0 + d1 * d1 + d2 * d2;
    __syncthreads();
    for (int s = 128; s > 0; s >>= 1) {
        if (tid < s) red[tid] += red[tid + s];
        __syncthreads();
    }
    const float var = red[0] * (1.0f / 767.0f);   // ddof=1
    const float inv = 1.0f / (sqrtf(var) + LNEPS);

    const size_t base = (size_t)m * HDIMT;
    if (isbf) {
        unsigned short* o = (unsigned short*)out;
        o[base + tid]       = f2bf(d0 * inv);
        o[base + tid + 256] = f2bf(d1 * inv);
        o[base + tid + 512] = f2bf(d2 * inv);
    } else {
        float* o = (float*)out;
        o[base + tid]       = d0 * inv;
        o[base + tid + 256] = d1 * inv;
        o[base + tid + 512] = d2 * inv;
    }
}

extern "C" void kernel_launch(void* const* d_in, const int* in_sizes, int n_in,
                              void* d_out, int out_size, void* d_ws, size_t ws_size,
                              hipStream_t stream)
{
    (void)in_sizes; (void)n_in; (void)out_size; (void)ws_size;

    const void* x  = d_in[0];
    const void* Wq = d_in[1];
    const void* bq = d_in[2];
    const void* Wk = d_in[3];
    const void* bk = d_in[4];
    const void* Wv = d_in[5];
    const void* bv = d_in[6];
    const void* Wo = d_in[7];
    const void* bo = d_in[8];

    float* ws  = (float*)d_ws;
    const size_t SZ = (size_t)MTOT * HDIMT;
    float* q   = ws;
    float* k   = ws + SZ;
    float* v   = ws + 2 * SZ;
    float* ctx = ws + 3 * SZ;
    float* y   = ws;                          // q dead after attention
    int* flag  = (int*)(ws + 4 * SZ);

    detect_kernel<<<1, 256, 0, stream>>>(x, flag);
    qkv_kernel<<<dim3(64, 12, 3), 256, 0, stream>>>(x, Wq, bq, Wk, bk, Wv, bv, q, k, v, flag);
    attn_kernel<<<dim3(32, 24), 256, 0, stream>>>(q, k, v, ctx, d_out, flag);
    oproj_kernel<<<dim3(64, 12), 256, 0, stream>>>(ctx, Wo, bo, x, y, flag);
    ln_kernel<<<MTOT, 256, 0, stream>>>(y, d_out, flag);
}